// Round 3
// baseline (3276.658 us; speedup 1.0000x reference)
//
#include <hip/hip_runtime.h>
#include <math.h>

#define NPTS 262144
#define TM   64      // points per block
#define NTHR 256     // 4 waves
#define AS   264     // act row stride (bf16 elems), 528B = 33*16B
#define PS   72      // pbuf row stride, 144B = 9*16B
#define WSS  40      // wbuf row stride, 80B = 5*16B

typedef short  short8  __attribute__((ext_vector_type(8)));
typedef short  short4v __attribute__((ext_vector_type(4)));
typedef float  floatx4 __attribute__((ext_vector_type(4)));

__device__ __forceinline__ unsigned short f2b(float f) {  // RNE
  union { float f; unsigned int i; } v; v.f = f;
  return (unsigned short)((v.i + 0x7fffu + ((v.i >> 16) & 1u)) >> 16);
}
__device__ __forceinline__ float b2f(unsigned short u) {
  union { unsigned int i; float f; } v; v.i = ((unsigned int)u) << 16; return v.f;
}

struct NerfArgs {
  const float* pts;
  const float* dirs;
  const float* Wb[8];
  const float* bias[10];   // bb0..bb7, brm, br0
  const float* Wrm;
  const float* Wr0;
  const float* Wsig;
  const float* bsig;
  const float* Wr1;
  const float* br1;
  float* out;
};

// One fused layer: D[64 x NF16*16] = relu(A[64 x Kp] @ W^T + bias) -> LDS bf16.
// A read from seg0 for first steps0 K-steps, then seg1. Weights are f32 in
// global; staged K-chunk (32) at a time into wbuf as bf16.
//   MODE 0: Ksrc == Kp (mult of 32) -> float4 vector stage
//   MODE 1: zero-pad cols >= Ksrc (scalar)
//   MODE 2: skip-layer remap [base(256) | p(63) | pad]: srccol = kp<256 ?
//           kp+63 : (kp<Ksrc ? kp-256 : -1)  (scalar)
template<int NF16, int MODE>
__device__ __forceinline__ void gemm(
    const float* wsrc, int Ksrc, int Kp,
    const short* seg0, int ld0, int steps0,
    const short* seg1, int ld1,
    const float* bias,
    short* dst, int ldd,
    short (*wbuf)[WSS], int tid)
{
  const int lane = tid & 63, wave = tid >> 6;
  const int steps = Kp >> 5;
  floatx4 acc[NF16];
  floatx4 zf = {0.f, 0.f, 0.f, 0.f};
#pragma unroll
  for (int i = 0; i < NF16; ++i) acc[i] = zf;
  const int arow = wave * 16 + (lane & 15);
  const int koff = (lane >> 4) * 8;
  const int brow = lane & 15;
  for (int s = 0; s < steps; ++s) {
    // stage W[:, s*32 .. s*32+31] (f32) into wbuf rows [0, NF16*16) as bf16
    if (MODE == 0) {
      for (int u = tid; u < NF16 * 16 * 8; u += NTHR) {
        int n = u >> 3, q = u & 7;
        const float4 w = *(const float4*)(wsrc + (size_t)n * Kp + s * 32 + q * 4);
        short4v b4;
        b4[0] = (short)f2b(w.x); b4[1] = (short)f2b(w.y);
        b4[2] = (short)f2b(w.z); b4[3] = (short)f2b(w.w);
        *(short4v*)&wbuf[n][q * 4] = b4;
      }
    } else {
      for (int u = tid; u < NF16 * 512; u += NTHR) {
        int n = u >> 5, c = u & 31;
        int kp = s * 32 + c, sc;
        if (MODE == 2) sc = (kp < 256) ? kp + 63 : (kp < Ksrc ? kp - 256 : -1);
        else           sc = (kp < Ksrc) ? kp : -1;
        wbuf[n][c] = (sc >= 0) ? (short)f2b(wsrc[(size_t)n * Ksrc + sc]) : (short)0;
      }
    }
    __syncthreads();
    const short* seg; int ld, kl;
    if (s < steps0) { seg = seg0; ld = ld0; kl = s * 32; }
    else            { seg = seg1; ld = ld1; kl = (s - steps0) * 32; }
    // A frag: A[m=lane&15][k=(lane>>4)*8+j] -> contiguous 16B ds_read
    short8 a = *(const short8*)(seg + (size_t)arow * ld + kl + koff);
#pragma unroll
    for (int nf = 0; nf < NF16; ++nf) {
      // B frag: B[k][n] = W[n][k] -> wbuf[n][k..k+7] contiguous 16B
      short8 b = *(const short8*)&wbuf[nf * 16 + brow][koff];
      acc[nf] = __builtin_amdgcn_mfma_f32_16x16x32_bf16(a, b, acc[nf], 0, 0, 0);
    }
    __syncthreads();
  }
  // epilogue: C/D layout row=(lane>>4)*4+r, col=lane&15
  const int crow = wave * 16 + (lane >> 4) * 4;
  const int ccol = lane & 15;
#pragma unroll
  for (int nf = 0; nf < NF16; ++nf) {
    int n = nf * 16 + ccol;
    float bv = bias[n];
#pragma unroll
    for (int r = 0; r < 4; ++r) {
      float v = fmaxf(acc[nf][r] + bv, 0.f);
      dst[(size_t)(crow + r) * ldd + n] = (short)f2b(v);
    }
  }
  __syncthreads();
}

__global__ __launch_bounds__(NTHR)
void nerf_fused(NerfArgs A) {
  __shared__ alignas(16) short act[TM][AS];     // 33792 B
  __shared__ alignas(16) short pbuf[TM][PS];    //  9216 B (p embed; later d embed)
  __shared__ alignas(16) short wbuf[256][WSS];  // 20480 B  total 63488 B
  const int tid = threadIdx.x;
  const size_t gbase = (size_t)blockIdx.x * TM;

  // phase 0: positional embed of pts into pbuf (cols 0..62; 63..71 zero)
  if (tid < TM) {
    int row = tid;
    size_t g = gbase + row;
    float x0 = A.pts[g * 3 + 0];
    float x1 = A.pts[g * 3 + 1];
    float x2 = A.pts[g * 3 + 2];
    short* pr = pbuf[row];
    pr[0] = (short)f2b(x0); pr[1] = (short)f2b(x1); pr[2] = (short)f2b(x2);
    float fr = 1.f;
    for (int q = 0; q < 10; ++q) {
      pr[3 + q * 6 + 0] = (short)f2b(sinf(x0 * fr));
      pr[3 + q * 6 + 1] = (short)f2b(sinf(x1 * fr));
      pr[3 + q * 6 + 2] = (short)f2b(sinf(x2 * fr));
      pr[3 + q * 6 + 3] = (short)f2b(cosf(x0 * fr));
      pr[3 + q * 6 + 4] = (short)f2b(cosf(x1 * fr));
      pr[3 + q * 6 + 5] = (short)f2b(cosf(x2 * fr));
      fr *= 2.f;
    }
    for (int c = 63; c < PS; ++c) pr[c] = 0;
  }
  __syncthreads();

  const short* actp = &act[0][0];
  short*       actw = &act[0][0];
  const short* pbp  = &pbuf[0][0];

  // base layers 0..5 (L5 input reordered as [base(256) | p(63) | pad], MODE 2)
  gemm<16, 1>(A.Wb[0], 63, 64, pbp, PS, 2, actp, AS, A.bias[0], actw, AS, wbuf, tid);
  gemm<16, 0>(A.Wb[1], 256, 256, actp, AS, 8, actp, AS, A.bias[1], actw, AS, wbuf, tid);
  gemm<16, 0>(A.Wb[2], 256, 256, actp, AS, 8, actp, AS, A.bias[2], actw, AS, wbuf, tid);
  gemm<16, 0>(A.Wb[3], 256, 256, actp, AS, 8, actp, AS, A.bias[3], actw, AS, wbuf, tid);
  gemm<16, 0>(A.Wb[4], 256, 256, actp, AS, 8, actp, AS, A.bias[4], actw, AS, wbuf, tid);
  gemm<16, 2>(A.Wb[5], 319, 320, actp, AS, 8, pbp, PS, A.bias[5], actw, AS, wbuf, tid);

  // p is dead: embed dirs into pbuf (cols 0..26; 27..31 zero) and emit d output (f32)
  if (tid >= 64 && tid < 128) {
    int row = tid - 64;
    size_t g = gbase + row;
    float x0 = A.dirs[g * 3 + 0];
    float x1 = A.dirs[g * 3 + 1];
    float x2 = A.dirs[g * 3 + 2];
    float vals[27];
    vals[0] = x0; vals[1] = x1; vals[2] = x2;
    float fr = 1.f;
    for (int q = 0; q < 4; ++q) {
      vals[3 + q * 6 + 0] = sinf(x0 * fr);
      vals[3 + q * 6 + 1] = sinf(x1 * fr);
      vals[3 + q * 6 + 2] = sinf(x2 * fr);
      vals[3 + q * 6 + 3] = cosf(x0 * fr);
      vals[3 + q * 6 + 4] = cosf(x1 * fr);
      vals[3 + q * 6 + 5] = cosf(x2 * fr);
      fr *= 2.f;
    }
    short* dr = pbuf[row];
    for (int j = 0; j < 27; ++j) {
      dr[j] = (short)f2b(vals[j]);
      A.out[(size_t)4 * NPTS + g * 27 + j] = vals[j];
    }
    for (int j = 27; j < 32; ++j) dr[j] = 0;
  }

  gemm<16, 0>(A.Wb[6], 256, 256, actp, AS, 8, actp, AS, A.bias[6], actw, AS, wbuf, tid);
  gemm<16, 0>(A.Wb[7], 256, 256, actp, AS, 8, actp, AS, A.bias[7], actw, AS, wbuf, tid);

  // sigma head from base (SIGMA_MUL=0 -> passthrough), f32
  if (tid < TM) {
    int row = tid;
    size_t g = gbase + row;
    float s = A.bsig[0];
    for (int k = 0; k < 256; ++k)
      s += b2f((unsigned short)act[row][k]) * A.Wsig[k];
    A.out[(size_t)3 * NPTS + g] = s;
  }

  // remap (256->256), then rgb_fea ([base_remap(256)|d(27)pad] -> 128)
  gemm<16, 0>(A.Wrm, 256, 256, actp, AS, 8, actp, AS, A.bias[8], actw, AS, wbuf, tid);
  gemm<8, 1>(A.Wr0, 283, 288, actp, AS, 8, pbp, PS, A.bias[9], actw, AS, wbuf, tid);

  // rgb head: sigmoid(fea @ Wr1^T + br1), f32
  if (tid < TM) {
    int row = tid;
    size_t g = gbase + row;
    float s0 = A.br1[0], s1 = A.br1[1], s2 = A.br1[2];
    for (int k = 0; k < 128; ++k) {
      float fv = b2f((unsigned short)act[row][k]);
      s0 += fv * A.Wr1[k];
      s1 += fv * A.Wr1[128 + k];
      s2 += fv * A.Wr1[256 + k];
    }
    A.out[g * 3 + 0] = 1.f / (1.f + expf(-s0));
    A.out[g * 3 + 1] = 1.f / (1.f + expf(-s1));
    A.out[g * 3 + 2] = 1.f / (1.f + expf(-s2));
  }
}

extern "C" void kernel_launch(void* const* d_in, const int* in_sizes, int n_in,
                              void* d_out, int out_size, void* d_ws, size_t ws_size,
                              hipStream_t stream) {
  // input order: pts, dirs, (Wb_i, bb_i)*8, Wsig, bsig, Wrm, brm, Wr0, br0, Wr1, br1
  NerfArgs na;
  na.pts  = (const float*)d_in[0];
  na.dirs = (const float*)d_in[1];
  for (int i = 0; i < 8; ++i) {
    na.Wb[i]   = (const float*)d_in[2 + 2 * i];
    na.bias[i] = (const float*)d_in[3 + 2 * i];
  }
  na.Wsig = (const float*)d_in[18];
  na.bsig = (const float*)d_in[19];
  na.Wrm  = (const float*)d_in[20];
  na.bias[8] = (const float*)d_in[21];  // brm
  na.Wr0  = (const float*)d_in[22];
  na.bias[9] = (const float*)d_in[23];  // br0
  na.Wr1  = (const float*)d_in[24];
  na.br1  = (const float*)d_in[25];
  na.out  = (float*)d_out;

  nerf_fused<<<dim3(NPTS / TM), dim3(NTHR), 0, stream>>>(na);
}

// Round 4
// 1439.628 us; speedup vs baseline: 2.2760x; 2.2760x over previous
//
#include <hip/hip_runtime.h>
#include <math.h>

#define NPTS 262144
#define TM   64      // points per block
#define NTHR 256     // 4 waves
#define AS   264     // act row stride (bf16 elems)
#define PS   72      // pbuf row stride
#define WSS  40      // slow-path wbuf row stride

#define WS_SHORTS 593920   // prepacked weight image size (bf16 elems)

typedef short  short8  __attribute__((ext_vector_type(8)));
typedef short  short4v __attribute__((ext_vector_type(4)));
typedef float  floatx4 __attribute__((ext_vector_type(4)));

__device__ __forceinline__ unsigned short f2b(float f) {  // RNE
  union { float f; unsigned int i; } v; v.f = f;
  return (unsigned short)((v.i + 0x7fffu + ((v.i >> 16) & 1u)) >> 16);
}
__device__ __forceinline__ float b2f(unsigned short u) {
  union { unsigned int i; float f; } v; v.i = ((unsigned int)u) << 16; return v.f;
}

// ======================= FAST PATH =======================
// Prepack all weights to bf16 in d_ws as per-K-chunk "fragment images":
// chunk c of a layer = 16 KB (NF16=16) laid out so that
//   offset_shorts = (n*4 + quad)*8 + j   with n=nf*16+brow, k = c*32+quad*8+j
// -> B-frag ds_read_b128 per nf is a contiguous 1KB block (canonical,
//    conflict-free), and staging is 4 coalesced int4 loads per thread.

struct PrepArgs {
  const float* src[10];
  unsigned short* ws;
  long long dst[10];
  int steps[10];
  int ksrc[10];
  int mode[10];   // 0: direct, 1: zero-pad >=ksrc, 2: L5 remap [base|p|pad]
  int nf16[10];
};

__global__ __launch_bounds__(256) void prep_weights(PrepArgs P) {
  int j = blockIdx.x, c = blockIdx.y;
  if (c >= P.steps[j]) return;
  const int NF = P.nf16[j], tot = NF * 512;
  const float* src = P.src[j];
  const int Ks = P.ksrc[j], mode = P.mode[j];
  unsigned short* dst = P.ws + P.dst[j] + (long long)c * tot;
  for (int u = threadIdx.x; u < tot; u += 256) {
    int n = u >> 5;
    int kp = c * 32 + (u & 31);
    int sc;
    if (mode == 0)      sc = kp;
    else if (mode == 1) sc = (kp < Ks) ? kp : -1;
    else                sc = (kp < 256) ? kp + 63 : (kp < Ks ? kp - 256 : -1);
    dst[u] = (sc >= 0) ? f2b(src[(long long)n * Ks + sc]) : (unsigned short)0;
  }
}

struct NerfFastArgs {
  const float* pts;
  const float* dirs;
  const unsigned short* ws;
  const float* bias[10];   // bb0..bb7, brm, br0
  const float* Wsig;
  const float* bsig;
  const float* Wr1;
  const float* br1;
  float* out;
};

// One layer: relu(A[64 x steps*32] @ W^T + bias) -> LDS bf16.
// Pipeline: pf(s+1) issued after the post-write barrier, consumed next step;
// its global latency hides behind compute(s).
template<int NF16>
__device__ __forceinline__ void gemm_fast(
    const unsigned short* wimg, int steps,
    const short* seg0, int ld0, int steps0,
    const short* seg1, int ld1,
    const float* bias, short* dst, int ldd,
    short* wbuf, int tid)
{
  const int lane = tid & 63, wave = tid >> 6;
  constexpr int CHB = NF16 * 1024;  // bytes per chunk image
  constexpr int NI  = NF16 / 4;     // int4 prefetch insts per thread
  floatx4 acc[NF16];
  floatx4 zf = {0.f, 0.f, 0.f, 0.f};
#pragma unroll
  for (int i = 0; i < NF16; ++i) acc[i] = zf;
  const int arow = wave * 16 + (lane & 15);
  const int koff = (lane >> 4) * 8;
  const int brow = lane & 15;
  const int slot = wave * 1024 + lane * 16;   // bytes within chunk image

  int4 pf[NI];
#pragma unroll
  for (int i = 0; i < NI; ++i)
    pf[i] = *(const int4*)((const char*)wimg + i * (NTHR * 16) + slot);

  for (int s = 0; s < steps; ++s) {
    __syncthreads();                 // all waves done reading previous chunk
#pragma unroll
    for (int i = 0; i < NI; ++i)     // canonical contiguous ds_write_b128
      *(int4*)((char*)wbuf + i * (NTHR * 16) + slot) = pf[i];
    __syncthreads();                 // chunk visible
    if (s + 1 < steps) {
#pragma unroll
      for (int i = 0; i < NI; ++i)   // prefetch next chunk; latency hides behind compute
        pf[i] = *(const int4*)((const char*)wimg + (size_t)(s + 1) * CHB + i * (NTHR * 16) + slot);
    }
    const short* seg; int ld, kl;
    if (s < steps0) { seg = seg0; ld = ld0; kl = s * 32; }
    else            { seg = seg1; ld = ld1; kl = (s - steps0) * 32; }
    // A frag: A[m=lane&15][k=(lane>>4)*8+j] -> contiguous 16B ds_read
    short8 a = *(const short8*)(seg + (size_t)arow * ld + kl + koff);
#pragma unroll
    for (int nf = 0; nf < NF16; ++nf) {
      // B frag: contiguous 1KB block per nf -> conflict-free
      short8 b = *(const short8*)(wbuf + nf * 512 + brow * 32 + koff);
      acc[nf] = __builtin_amdgcn_mfma_f32_16x16x32_bf16(a, b, acc[nf], 0, 0, 0);
    }
  }
  // epilogue: C/D layout row=(lane>>4)*4+r, col=lane&15 (each wave owns its rows)
  const int crow = wave * 16 + (lane >> 4) * 4;
  const int ccol = lane & 15;
#pragma unroll
  for (int nf = 0; nf < NF16; ++nf) {
    int n = nf * 16 + ccol;
    float bv = bias[n];
#pragma unroll
    for (int r = 0; r < 4; ++r) {
      float v = fmaxf(acc[nf][r] + bv, 0.f);
      dst[(size_t)(crow + r) * ldd + n] = (short)f2b(v);
    }
  }
  __syncthreads();
}

__global__ __launch_bounds__(NTHR)
void nerf_fused_fast(NerfFastArgs A) {
  __shared__ alignas(16) short act[TM][AS];   // 33792 B
  __shared__ alignas(16) short pbuf[TM][PS];  //  9216 B
  __shared__ alignas(16) short wbuf[8192];    // 16384 B   total 59392 B -> 2 blocks/CU
  const int tid = threadIdx.x;
  const size_t gbase = (size_t)blockIdx.x * TM;

  // phase 0: positional embed of pts into pbuf (cols 0..62; 63..71 zero)
  if (tid < TM) {
    int row = tid;
    size_t g = gbase + row;
    float x0 = A.pts[g * 3 + 0];
    float x1 = A.pts[g * 3 + 1];
    float x2 = A.pts[g * 3 + 2];
    short* pr = pbuf[row];
    pr[0] = (short)f2b(x0); pr[1] = (short)f2b(x1); pr[2] = (short)f2b(x2);
    float fr = 1.f;
    for (int q = 0; q < 10; ++q) {
      pr[3 + q * 6 + 0] = (short)f2b(sinf(x0 * fr));
      pr[3 + q * 6 + 1] = (short)f2b(sinf(x1 * fr));
      pr[3 + q * 6 + 2] = (short)f2b(sinf(x2 * fr));
      pr[3 + q * 6 + 3] = (short)f2b(cosf(x0 * fr));
      pr[3 + q * 6 + 4] = (short)f2b(cosf(x1 * fr));
      pr[3 + q * 6 + 5] = (short)f2b(cosf(x2 * fr));
      fr *= 2.f;
    }
    for (int c = 63; c < PS; ++c) pr[c] = 0;
  }
  __syncthreads();

  const short* actp = &act[0][0];
  short*       actw = &act[0][0];
  const short* pbp  = &pbuf[0][0];
  const unsigned short* ws = A.ws;

  gemm_fast<16>(ws + 0,      2,  pbp, PS, 2, actp, AS, A.bias[0], actw, AS, wbuf, tid);
  gemm_fast<16>(ws + 16384,  8,  actp, AS, 8, actp, AS, A.bias[1], actw, AS, wbuf, tid);
  gemm_fast<16>(ws + 81920,  8,  actp, AS, 8, actp, AS, A.bias[2], actw, AS, wbuf, tid);
  gemm_fast<16>(ws + 147456, 8,  actp, AS, 8, actp, AS, A.bias[3], actw, AS, wbuf, tid);
  gemm_fast<16>(ws + 212992, 8,  actp, AS, 8, actp, AS, A.bias[4], actw, AS, wbuf, tid);
  gemm_fast<16>(ws + 278528, 10, actp, AS, 8, pbp,  PS, A.bias[5], actw, AS, wbuf, tid);

  // p dead: embed dirs into pbuf (cols 0..26; 27..31 zero) and emit d output (f32)
  if (tid >= 64 && tid < 128) {
    int row = tid - 64;
    size_t g = gbase + row;
    float x0 = A.dirs[g * 3 + 0];
    float x1 = A.dirs[g * 3 + 1];
    float x2 = A.dirs[g * 3 + 2];
    float vals[27];
    vals[0] = x0; vals[1] = x1; vals[2] = x2;
    float fr = 1.f;
    for (int q = 0; q < 4; ++q) {
      vals[3 + q * 6 + 0] = sinf(x0 * fr);
      vals[3 + q * 6 + 1] = sinf(x1 * fr);
      vals[3 + q * 6 + 2] = sinf(x2 * fr);
      vals[3 + q * 6 + 3] = cosf(x0 * fr);
      vals[3 + q * 6 + 4] = cosf(x1 * fr);
      vals[3 + q * 6 + 5] = cosf(x2 * fr);
      fr *= 2.f;
    }
    short* dr = pbuf[row];
    for (int j = 0; j < 27; ++j) {
      dr[j] = (short)f2b(vals[j]);
      A.out[(size_t)4 * NPTS + g * 27 + j] = vals[j];
    }
    for (int j = 27; j < 32; ++j) dr[j] = 0;
  }

  gemm_fast<16>(ws + 360448, 8, actp, AS, 8, actp, AS, A.bias[6], actw, AS, wbuf, tid);
  gemm_fast<16>(ws + 425984, 8, actp, AS, 8, actp, AS, A.bias[7], actw, AS, wbuf, tid);

  // sigma head (SIGMA_MUL=0 -> passthrough), f32
  if (tid < TM) {
    int row = tid;
    size_t g = gbase + row;
    float s = A.bsig[0];
    for (int k = 0; k < 256; ++k)
      s += b2f((unsigned short)act[row][k]) * A.Wsig[k];
    A.out[(size_t)3 * NPTS + g] = s;
  }

  gemm_fast<16>(ws + 491520, 8, actp, AS, 8, actp, AS, A.bias[8], actw, AS, wbuf, tid);
  gemm_fast<8>( ws + 557056, 9, actp, AS, 8, pbp,  PS, A.bias[9], actw, AS, wbuf, tid);

  // rgb head: sigmoid(fea @ Wr1^T + br1), f32
  if (tid < TM) {
    int row = tid;
    size_t g = gbase + row;
    float s0 = A.br1[0], s1 = A.br1[1], s2 = A.br1[2];
    for (int k = 0; k < 128; ++k) {
      float fv = b2f((unsigned short)act[row][k]);
      s0 += fv * A.Wr1[k];
      s1 += fv * A.Wr1[128 + k];
      s2 += fv * A.Wr1[256 + k];
    }
    A.out[g * 3 + 0] = 1.f / (1.f + expf(-s0));
    A.out[g * 3 + 1] = 1.f / (1.f + expf(-s1));
    A.out[g * 3 + 2] = 1.f / (1.f + expf(-s2));
  }
}

// ======================= SLOW PATH (R3, proven; used if ws too small) =======================
struct NerfArgs {
  const float* pts;
  const float* dirs;
  const float* Wb[8];
  const float* bias[10];
  const float* Wrm;
  const float* Wr0;
  const float* Wsig;
  const float* bsig;
  const float* Wr1;
  const float* br1;
  float* out;
};

template<int NF16, int MODE>
__device__ __forceinline__ void gemm_slow(
    const float* wsrc, int Ksrc, int Kp,
    const short* seg0, int ld0, int steps0,
    const short* seg1, int ld1,
    const float* bias,
    short* dst, int ldd,
    short (*wbuf)[WSS], int tid)
{
  const int lane = tid & 63, wave = tid >> 6;
  const int steps = Kp >> 5;
  floatx4 acc[NF16];
  floatx4 zf = {0.f, 0.f, 0.f, 0.f};
#pragma unroll
  for (int i = 0; i < NF16; ++i) acc[i] = zf;
  const int arow = wave * 16 + (lane & 15);
  const int koff = (lane >> 4) * 8;
  const int brow = lane & 15;
  for (int s = 0; s < steps; ++s) {
    if (MODE == 0) {
      for (int u = tid; u < NF16 * 16 * 8; u += NTHR) {
        int n = u >> 3, q = u & 7;
        const float4 w = *(const float4*)(wsrc + (size_t)n * Kp + s * 32 + q * 4);
        short4v b4;
        b4[0] = (short)f2b(w.x); b4[1] = (short)f2b(w.y);
        b4[2] = (short)f2b(w.z); b4[3] = (short)f2b(w.w);
        *(short4v*)&wbuf[n][q * 4] = b4;
      }
    } else {
      for (int u = tid; u < NF16 * 512; u += NTHR) {
        int n = u >> 5, c = u & 31;
        int kp = s * 32 + c, sc;
        if (MODE == 2) sc = (kp < 256) ? kp + 63 : (kp < Ksrc ? kp - 256 : -1);
        else           sc = (kp < Ksrc) ? kp : -1;
        wbuf[n][c] = (sc >= 0) ? (short)f2b(wsrc[(size_t)n * Ksrc + sc]) : (short)0;
      }
    }
    __syncthreads();
    const short* seg; int ld, kl;
    if (s < steps0) { seg = seg0; ld = ld0; kl = s * 32; }
    else            { seg = seg1; ld = ld1; kl = (s - steps0) * 32; }
    short8 a = *(const short8*)(seg + (size_t)arow * ld + kl + koff);
#pragma unroll
    for (int nf = 0; nf < NF16; ++nf) {
      short8 b = *(const short8*)&wbuf[nf * 16 + brow][koff];
      acc[nf] = __builtin_amdgcn_mfma_f32_16x16x32_bf16(a, b, acc[nf], 0, 0, 0);
    }
    __syncthreads();
  }
  const int crow = wave * 16 + (lane >> 4) * 4;
  const int ccol = lane & 15;
#pragma unroll
  for (int nf = 0; nf < NF16; ++nf) {
    int n = nf * 16 + ccol;
    float bv = bias[n];
#pragma unroll
    for (int r = 0; r < 4; ++r) {
      float v = fmaxf(acc[nf][r] + bv, 0.f);
      dst[(size_t)(crow + r) * ldd + n] = (short)f2b(v);
    }
  }
  __syncthreads();
}

__global__ __launch_bounds__(NTHR)
void nerf_fused_slow(NerfArgs A) {
  __shared__ alignas(16) short act[TM][AS];
  __shared__ alignas(16) short pbuf[TM][PS];
  __shared__ alignas(16) short wbuf[256][WSS];
  const int tid = threadIdx.x;
  const size_t gbase = (size_t)blockIdx.x * TM;

  if (tid < TM) {
    int row = tid;
    size_t g = gbase + row;
    float x0 = A.pts[g * 3 + 0];
    float x1 = A.pts[g * 3 + 1];
    float x2 = A.pts[g * 3 + 2];
    short* pr = pbuf[row];
    pr[0] = (short)f2b(x0); pr[1] = (short)f2b(x1); pr[2] = (short)f2b(x2);
    float fr = 1.f;
    for (int q = 0; q < 10; ++q) {
      pr[3 + q * 6 + 0] = (short)f2b(sinf(x0 * fr));
      pr[3 + q * 6 + 1] = (short)f2b(sinf(x1 * fr));
      pr[3 + q * 6 + 2] = (short)f2b(sinf(x2 * fr));
      pr[3 + q * 6 + 3] = (short)f2b(cosf(x0 * fr));
      pr[3 + q * 6 + 4] = (short)f2b(cosf(x1 * fr));
      pr[3 + q * 6 + 5] = (short)f2b(cosf(x2 * fr));
      fr *= 2.f;
    }
    for (int c = 63; c < PS; ++c) pr[c] = 0;
  }
  __syncthreads();

  const short* actp = &act[0][0];
  short*       actw = &act[0][0];
  const short* pbp  = &pbuf[0][0];

  gemm_slow<16, 1>(A.Wb[0], 63, 64, pbp, PS, 2, actp, AS, A.bias[0], actw, AS, wbuf, tid);
  gemm_slow<16, 0>(A.Wb[1], 256, 256, actp, AS, 8, actp, AS, A.bias[1], actw, AS, wbuf, tid);
  gemm_slow<16, 0>(A.Wb[2], 256, 256, actp, AS, 8, actp, AS, A.bias[2], actw, AS, wbuf, tid);
  gemm_slow<16, 0>(A.Wb[3], 256, 256, actp, AS, 8, actp, AS, A.bias[3], actw, AS, wbuf, tid);
  gemm_slow<16, 0>(A.Wb[4], 256, 256, actp, AS, 8, actp, AS, A.bias[4], actw, AS, wbuf, tid);
  gemm_slow<16, 2>(A.Wb[5], 319, 320, actp, AS, 8, pbp, PS, A.bias[5], actw, AS, wbuf, tid);

  if (tid >= 64 && tid < 128) {
    int row = tid - 64;
    size_t g = gbase + row;
    float x0 = A.dirs[g * 3 + 0];
    float x1 = A.dirs[g * 3 + 1];
    float x2 = A.dirs[g * 3 + 2];
    float vals[27];
    vals[0] = x0; vals[1] = x1; vals[2] = x2;
    float fr = 1.f;
    for (int q = 0; q < 4; ++q) {
      vals[3 + q * 6 + 0] = sinf(x0 * fr);
      vals[3 + q * 6 + 1] = sinf(x1 * fr);
      vals[3 + q * 6 + 2] = sinf(x2 * fr);
      vals[3 + q * 6 + 3] = cosf(x0 * fr);
      vals[3 + q * 6 + 4] = cosf(x1 * fr);
      vals[3 + q * 6 + 5] = cosf(x2 * fr);
      fr *= 2.f;
    }
    short* dr = pbuf[row];
    for (int j = 0; j < 27; ++j) {
      dr[j] = (short)f2b(vals[j]);
      A.out[(size_t)4 * NPTS + g * 27 + j] = vals[j];
    }
    for (int j = 27; j < 32; ++j) dr[j] = 0;
  }

  gemm_slow<16, 0>(A.Wb[6], 256, 256, actp, AS, 8, actp, AS, A.bias[6], actw, AS, wbuf, tid);
  gemm_slow<16, 0>(A.Wb[7], 256, 256, actp, AS, 8, actp, AS, A.bias[7], actw, AS, wbuf, tid);

  if (tid < TM) {
    int row = tid;
    size_t g = gbase + row;
    float s = A.bsig[0];
    for (int k = 0; k < 256; ++k)
      s += b2f((unsigned short)act[row][k]) * A.Wsig[k];
    A.out[(size_t)3 * NPTS + g] = s;
  }

  gemm_slow<16, 0>(A.Wrm, 256, 256, actp, AS, 8, actp, AS, A.bias[8], actw, AS, wbuf, tid);
  gemm_slow<8, 1>(A.Wr0, 283, 288, actp, AS, 8, pbp, PS, A.bias[9], actw, AS, wbuf, tid);

  if (tid < TM) {
    int row = tid;
    size_t g = gbase + row;
    float s0 = A.br1[0], s1 = A.br1[1], s2 = A.br1[2];
    for (int k = 0; k < 128; ++k) {
      float fv = b2f((unsigned short)act[row][k]);
      s0 += fv * A.Wr1[k];
      s1 += fv * A.Wr1[128 + k];
      s2 += fv * A.Wr1[256 + k];
    }
    A.out[g * 3 + 0] = 1.f / (1.f + expf(-s0));
    A.out[g * 3 + 1] = 1.f / (1.f + expf(-s1));
    A.out[g * 3 + 2] = 1.f / (1.f + expf(-s2));
  }
}

extern "C" void kernel_launch(void* const* d_in, const int* in_sizes, int n_in,
                              void* d_out, int out_size, void* d_ws, size_t ws_size,
                              hipStream_t stream) {
  // input order: pts, dirs, (Wb_i, bb_i)*8, Wsig, bsig, Wrm, brm, Wr0, br0, Wr1, br1
  if (ws_size >= (size_t)WS_SHORTS * 2) {
    PrepArgs pp;
    const int       widx[10]  = {2, 4, 6, 8, 10, 12, 14, 16, 20, 22};
    const long long doffs[10] = {0, 16384, 81920, 147456, 212992, 278528,
                                 360448, 425984, 491520, 557056};
    const int stv[10] = {2, 8, 8, 8, 8, 10, 8, 8, 8, 9};
    const int ksv[10] = {63, 256, 256, 256, 256, 319, 256, 256, 256, 283};
    const int mdv[10] = {1, 0, 0, 0, 0, 2, 0, 0, 0, 1};
    const int nfv[10] = {16, 16, 16, 16, 16, 16, 16, 16, 16, 8};
    pp.ws = (unsigned short*)d_ws;
    for (int j = 0; j < 10; ++j) {
      pp.src[j] = (const float*)d_in[widx[j]];
      pp.dst[j] = doffs[j]; pp.steps[j] = stv[j]; pp.ksrc[j] = ksv[j];
      pp.mode[j] = mdv[j]; pp.nf16[j] = nfv[j];
    }
    prep_weights<<<dim3(10, 10), dim3(256), 0, stream>>>(pp);

    NerfFastArgs na;
    na.pts  = (const float*)d_in[0];
    na.dirs = (const float*)d_in[1];
    na.ws   = (const unsigned short*)d_ws;
    for (int i = 0; i < 8; ++i) na.bias[i] = (const float*)d_in[3 + 2 * i];
    na.bias[8] = (const float*)d_in[21];
    na.bias[9] = (const float*)d_in[23];
    na.Wsig = (const float*)d_in[18];
    na.bsig = (const float*)d_in[19];
    na.Wr1  = (const float*)d_in[24];
    na.br1  = (const float*)d_in[25];
    na.out  = (float*)d_out;
    nerf_fused_fast<<<dim3(NPTS / TM), dim3(NTHR), 0, stream>>>(na);
  } else {
    NerfArgs na;
    na.pts  = (const float*)d_in[0];
    na.dirs = (const float*)d_in[1];
    for (int i = 0; i < 8; ++i) {
      na.Wb[i]   = (const float*)d_in[2 + 2 * i];
      na.bias[i] = (const float*)d_in[3 + 2 * i];
    }
    na.Wsig = (const float*)d_in[18];
    na.bsig = (const float*)d_in[19];
    na.Wrm  = (const float*)d_in[20];
    na.bias[8] = (const float*)d_in[21];
    na.Wr0  = (const float*)d_in[22];
    na.bias[9] = (const float*)d_in[23];
    na.Wr1  = (const float*)d_in[24];
    na.br1  = (const float*)d_in[25];
    na.out  = (float*)d_out;
    nerf_fused_slow<<<dim3(NPTS / TM), dim3(NTHR), 0, stream>>>(na);
  }
}

// Round 5
// 441.991 us; speedup vs baseline: 7.4134x; 3.2571x over previous
//
#include <hip/hip_runtime.h>
#include <math.h>

#define NPTS 262144
#define TM   64      // points per block
#define NTHR 256     // 4 waves
#define AS   264     // act row stride (bf16 elems): 528B rows, shifts bank groups by 4/row
#define PS   72      // pbuf row stride

#define WS_SHORTS 593920   // prepacked weight image (bf16 elems)

typedef short  short8  __attribute__((ext_vector_type(8)));
typedef float  floatx4 __attribute__((ext_vector_type(4)));

__device__ __forceinline__ unsigned short f2b(float f) {  // RNE
  union { float f; unsigned int i; } v; v.f = f;
  return (unsigned short)((v.i + 0x7fffu + ((v.i >> 16) & 1u)) >> 16);
}
__device__ __forceinline__ float b2f(unsigned short u) {
  union { unsigned int i; float f; } v; v.i = ((unsigned int)u) << 16; return v.f;
}

// ---------------- weight prepack: B-fragment order ----------------
// image element u within chunk c of a layer:
//   u = nf*512 + lane*8 + j  ->  W[n = nf*16 + (lane&15)][k = c*32 + (lane>>4)*8 + j]
// so a wave's B-frag load for tile nf is ONE coalesced 1KB global_load_dwordx4.
struct PrepArgs {
  const float* src[10];
  unsigned short* ws;
  long long dst[10];
  int steps[10];
  int ksrc[10];
  int mode[10];   // 0: direct, 1: zero-pad >=ksrc, 2: L5 remap [base(256)|p(63)|pad]
  int nf16[10];
};

__global__ __launch_bounds__(256) void prep_weights(PrepArgs P) {
  int jl = blockIdx.x, c = blockIdx.y;
  if (c >= P.steps[jl]) return;
  const int NF = P.nf16[jl], tot = NF * 512;
  const float* src = P.src[jl];
  const int Ks = P.ksrc[jl], mode = P.mode[jl];
  unsigned short* dst = P.ws + P.dst[jl] + (long long)c * tot;
  for (int u = threadIdx.x; u < tot; u += 256) {
    int j = u & 7, lane = (u >> 3) & 63, nf = u >> 9;
    int n  = nf * 16 + (lane & 15);
    int kp = c * 32 + ((lane >> 4) << 3) + j;
    int sc;
    if (mode == 0)      sc = kp;
    else if (mode == 1) sc = (kp < Ks) ? kp : -1;
    else                sc = (kp < 256) ? kp + 63 : (kp < Ks ? kp - 256 : -1);
    dst[u] = (sc >= 0) ? f2b(src[(long long)n * Ks + sc]) : (unsigned short)0;
  }
}

struct NerfArgs {
  const float* pts;
  const float* dirs;
  const unsigned short* ws;
  const float* bias[10];   // bb0..bb7, brm, br0
  const float* Wsig;
  const float* bsig;
  const float* Wr1;
  const float* br1;
  float* out;
};

// One layer: relu(A[64 x steps*32] @ W^T + bias) -> LDS bf16 (in-place safe).
// Wave w owns output cols [w*NFW*16, (w+1)*NFW*16); B-frags stream from global
// (L2-hot prepacked image) with 1-step register prefetch; A-frags from LDS.
// No barriers inside the K-loop.
template<int NFTOT, int NFW>
__device__ __forceinline__ void gemm_g(
    const unsigned short* wimg, int steps,
    const short* seg0, int ld0, int steps0,
    const short* seg1, int ld1,
    const float* bias, short* dst, int ldd, int tid)
{
  const int lane = tid & 63, wave = tid >> 6;
  floatx4 acc[4][NFW];
  floatx4 zf = {0.f, 0.f, 0.f, 0.f};
#pragma unroll
  for (int mf = 0; mf < 4; ++mf)
#pragma unroll
    for (int i = 0; i < NFW; ++i) acc[mf][i] = zf;

  const int abase = lane & 15;          // m within 16-tile
  const int koff  = (lane >> 4) * 8;    // k sub-offset
  const unsigned short* wl = wimg + (size_t)(wave * NFW) * 512 + (size_t)lane * 8;

  short8 bcur[NFW], bnxt[NFW];
#pragma unroll
  for (int i = 0; i < NFW; ++i) bcur[i] = *(const short8*)(wl + i * 512);

  for (int s = 0; s < steps; ++s) {
    if (s + 1 < steps) {
      const unsigned short* wn = wl + (size_t)(s + 1) * (NFTOT * 512);
#pragma unroll
      for (int i = 0; i < NFW; ++i) bnxt[i] = *(const short8*)(wn + i * 512);
    }
    const short* seg; int ld, kl;
    if (s < steps0) { seg = seg0; ld = ld0; kl = s * 32; }
    else            { seg = seg1; ld = ld1; kl = (s - steps0) * 32; }
    short8 a[4];
#pragma unroll
    for (int mf = 0; mf < 4; ++mf)   // A[m=mf*16+(lane&15)][k=kl+koff..+7], 16B ds_read
      a[mf] = *(const short8*)(seg + (size_t)(mf * 16 + abase) * ld + kl + koff);
#pragma unroll
    for (int mf = 0; mf < 4; ++mf)
#pragma unroll
      for (int i = 0; i < NFW; ++i)
        acc[mf][i] = __builtin_amdgcn_mfma_f32_16x16x32_bf16(a[mf], bcur[i], acc[mf][i], 0, 0, 0);
    if (s + 1 < steps) {
#pragma unroll
      for (int i = 0; i < NFW; ++i) bcur[i] = bnxt[i];
    }
  }
  __syncthreads();   // all waves' A reads complete before in-place writes
  // C/D layout: row = (lane>>4)*4 + r (within mf tile), col = lane&15
  const int cr4  = (lane >> 4) * 4;
  const int ccol = lane & 15;
#pragma unroll
  for (int i = 0; i < NFW; ++i) {
    int n = (wave * NFW + i) * 16 + ccol;
    float bv = bias[n];
#pragma unroll
    for (int mf = 0; mf < 4; ++mf) {
      int crow = mf * 16 + cr4;
#pragma unroll
      for (int r = 0; r < 4; ++r) {
        float v = fmaxf(acc[mf][i][r] + bv, 0.f);
        dst[(size_t)(crow + r) * ldd + n] = (short)f2b(v);
      }
    }
  }
  __syncthreads();
}

__global__ __launch_bounds__(NTHR, 3)
void nerf_fused(NerfArgs A) {
  __shared__ alignas(16) short act[TM][AS];   // 33792 B
  __shared__ alignas(16) short pbuf[TM][PS];  //  9216 B   total 43008 B -> 3 blocks/CU
  const int tid = threadIdx.x;
  const size_t gbase = (size_t)blockIdx.x * TM;

  // positional embed of pts into pbuf (cols 0..62; 63..71 zero)
  if (tid < TM) {
    int row = tid;
    size_t g = gbase + row;
    float x0 = A.pts[g * 3 + 0];
    float x1 = A.pts[g * 3 + 1];
    float x2 = A.pts[g * 3 + 2];
    short* pr = pbuf[row];
    pr[0] = (short)f2b(x0); pr[1] = (short)f2b(x1); pr[2] = (short)f2b(x2);
    float fr = 1.f;
    for (int q = 0; q < 10; ++q) {
      pr[3 + q * 6 + 0] = (short)f2b(sinf(x0 * fr));
      pr[3 + q * 6 + 1] = (short)f2b(sinf(x1 * fr));
      pr[3 + q * 6 + 2] = (short)f2b(sinf(x2 * fr));
      pr[3 + q * 6 + 3] = (short)f2b(cosf(x0 * fr));
      pr[3 + q * 6 + 4] = (short)f2b(cosf(x1 * fr));
      pr[3 + q * 6 + 5] = (short)f2b(cosf(x2 * fr));
      fr *= 2.f;
    }
    for (int c = 63; c < PS; ++c) pr[c] = 0;
  }
  __syncthreads();

  const short* actp = &act[0][0];
  short*       actw = &act[0][0];
  const short* pbp  = &pbuf[0][0];
  const unsigned short* ws = A.ws;

  gemm_g<16, 4>(ws + 0,      2,  pbp, PS, 2, actp, AS, A.bias[0], actw, AS, tid);
  gemm_g<16, 4>(ws + 16384,  8,  actp, AS, 8, actp, AS, A.bias[1], actw, AS, tid);
  gemm_g<16, 4>(ws + 81920,  8,  actp, AS, 8, actp, AS, A.bias[2], actw, AS, tid);
  gemm_g<16, 4>(ws + 147456, 8,  actp, AS, 8, actp, AS, A.bias[3], actw, AS, tid);
  gemm_g<16, 4>(ws + 212992, 8,  actp, AS, 8, actp, AS, A.bias[4], actw, AS, tid);
  gemm_g<16, 4>(ws + 278528, 10, actp, AS, 8, pbp,  PS, A.bias[5], actw, AS, tid);

  // p dead: embed dirs into pbuf (cols 0..26; 27..31 zero) and emit d output (f32)
  if (tid >= 64 && tid < 128) {
    int row = tid - 64;
    size_t g = gbase + row;
    float x0 = A.dirs[g * 3 + 0];
    float x1 = A.dirs[g * 3 + 1];
    float x2 = A.dirs[g * 3 + 2];
    float vals[27];
    vals[0] = x0; vals[1] = x1; vals[2] = x2;
    float fr = 1.f;
    for (int q = 0; q < 4; ++q) {
      vals[3 + q * 6 + 0] = sinf(x0 * fr);
      vals[3 + q * 6 + 1] = sinf(x1 * fr);
      vals[3 + q * 6 + 2] = sinf(x2 * fr);
      vals[3 + q * 6 + 3] = cosf(x0 * fr);
      vals[3 + q * 6 + 4] = cosf(x1 * fr);
      vals[3 + q * 6 + 5] = cosf(x2 * fr);
      fr *= 2.f;
    }
    short* dr = pbuf[row];
    for (int j = 0; j < 27; ++j) {
      dr[j] = (short)f2b(vals[j]);
      A.out[(size_t)4 * NPTS + g * 27 + j] = vals[j];
    }
    for (int j = 27; j < 32; ++j) dr[j] = 0;
  }

  gemm_g<16, 4>(ws + 360448, 8, actp, AS, 8, actp, AS, A.bias[6], actw, AS, tid);
  gemm_g<16, 4>(ws + 425984, 8, actp, AS, 8, actp, AS, A.bias[7], actw, AS, tid);

  // sigma head (SIGMA_MUL=0 -> passthrough), f32
  if (tid < TM) {
    int row = tid;
    size_t g = gbase + row;
    float s = A.bsig[0];
    for (int k = 0; k < 256; ++k)
      s += b2f((unsigned short)act[row][k]) * A.Wsig[k];
    A.out[(size_t)3 * NPTS + g] = s;
  }
  // sigma reads of act complete (program order) before rm's post-K-loop barrier
  gemm_g<16, 4>(ws + 491520, 8, actp, AS, 8, actp, AS, A.bias[8], actw, AS, tid);
  gemm_g<8, 2>( ws + 557056, 9, actp, AS, 8, pbp,  PS, A.bias[9], actw, AS, tid);

  // rgb head: sigmoid(fea @ Wr1^T + br1), f32
  if (tid < TM) {
    int row = tid;
    size_t g = gbase + row;
    float s0 = A.br1[0], s1 = A.br1[1], s2 = A.br1[2];
    for (int k = 0; k < 128; ++k) {
      float fv = b2f((unsigned short)act[row][k]);
      s0 += fv * A.Wr1[k];
      s1 += fv * A.Wr1[128 + k];
      s2 += fv * A.Wr1[256 + k];
    }
    A.out[g * 3 + 0] = 1.f / (1.f + expf(-s0));
    A.out[g * 3 + 1] = 1.f / (1.f + expf(-s1));
    A.out[g * 3 + 2] = 1.f / (1.f + expf(-s2));
  }
}

extern "C" void kernel_launch(void* const* d_in, const int* in_sizes, int n_in,
                              void* d_out, int out_size, void* d_ws, size_t ws_size,
                              hipStream_t stream) {
  // input order: pts, dirs, (Wb_i, bb_i)*8, Wsig, bsig, Wrm, brm, Wr0, br0, Wr1, br1
  PrepArgs pp;
  const int       widx[10]  = {2, 4, 6, 8, 10, 12, 14, 16, 20, 22};
  const long long doffs[10] = {0, 16384, 81920, 147456, 212992, 278528,
                               360448, 425984, 491520, 557056};
  const int stv[10] = {2, 8, 8, 8, 8, 10, 8, 8, 8, 9};
  const int ksv[10] = {63, 256, 256, 256, 256, 319, 256, 256, 256, 283};
  const int mdv[10] = {1, 0, 0, 0, 0, 2, 0, 0, 0, 1};
  const int nfv[10] = {16, 16, 16, 16, 16, 16, 16, 16, 16, 8};
  pp.ws = (unsigned short*)d_ws;   // needs WS_SHORTS*2 = 1.19 MB (verified in R4)
  for (int j = 0; j < 10; ++j) {
    pp.src[j] = (const float*)d_in[widx[j]];
    pp.dst[j] = doffs[j]; pp.steps[j] = stv[j]; pp.ksrc[j] = ksv[j];
    pp.mode[j] = mdv[j]; pp.nf16[j] = nfv[j];
  }
  prep_weights<<<dim3(10, 10), dim3(256), 0, stream>>>(pp);

  NerfArgs na;
  na.pts  = (const float*)d_in[0];
  na.dirs = (const float*)d_in[1];
  na.ws   = (const unsigned short*)d_ws;
  for (int i = 0; i < 8; ++i) na.bias[i] = (const float*)d_in[3 + 2 * i];
  na.bias[8] = (const float*)d_in[21];  // brm
  na.bias[9] = (const float*)d_in[23];  // br0
  na.Wsig = (const float*)d_in[18];
  na.bsig = (const float*)d_in[19];
  na.Wr1  = (const float*)d_in[24];
  na.br1  = (const float*)d_in[25];
  na.out  = (float*)d_out;
  nerf_fused<<<dim3(NPTS / TM), dim3(NTHR), 0, stream>>>(na);
}